// Round 2
// baseline (126.083 us; speedup 1.0000x reference)
//
#include <hip/hip_runtime.h>
#include <math.h>

#define BB 8
#define SS 4096
#define DD 1024
#define HH 16

typedef __attribute__((ext_vector_type(8))) short short8;
typedef __attribute__((ext_vector_type(4))) float f32x4;

// ws layout:
//   logits/weights [BB][SS][HH] fp32  = 2 MB   (offset 0)
//   partial [32][BB][HH][DD] fp32     = 16 MB  (offset 2 MB)
//   whi/wlo frag streams (32+32 KB) ALIAS the partial region: written by K0,
//   read by K1, then overwritten by K3 (strictly later on the same stream).

__device__ __forceinline__ ushort bf16_rne(float f) {
  unsigned b = __float_as_uint(f);
  return (ushort)((b + 0x7fffu + ((b >> 16) & 1u)) >> 16);
}

// K0: precompute W frag streams. Frag map (must match K1's A-frag map):
// element e of lane l at K-step t corresponds to k = t*32 + (l>>4)*8 + e,
// B-frag col = l&15. whi/wlo layout: [t][lane][e] ushort.
__global__ __launch_bounds__(256) void k_prepw(
    const float* __restrict__ W, ushort* __restrict__ whi, ushort* __restrict__ wlo) {
  int i = blockIdx.x * 256 + threadIdx.x;  // 16384 total
  int t = i >> 9;
  int l = (i >> 3) & 63;
  int e = i & 7;
  int d = t * 32 + (l >> 4) * 8 + e;
  int h = l & 15;
  float w = W[d * HH + h];
  unsigned b = __float_as_uint(w);
  whi[i] = (ushort)(b >> 16);                       // truncated hi
  float hf = __uint_as_float(b & 0xffff0000u);
  wlo[i] = bf16_rne(w - hf);                        // RNE lo (residual <= 2^-16)
}

// K1: logits via MFMA 16x16x32 bf16, split-precision (hihi + hilo + lohi).
// grid 512 (= 8 b * 64 s-tiles of 64 rows), block 256 (4 waves, 16 rows each).
#define XSTRIDE 132  // 128 + 4: keeps float4 alignment, spreads banks
__global__ __launch_bounds__(256) void k_logits(
    const float* __restrict__ x, const ushort* __restrict__ whi,
    const ushort* __restrict__ wlo, const int* __restrict__ mask,
    float* __restrict__ logits) {
  __shared__ float xt[64 * XSTRIDE];

  const int tid = threadIdx.x;
  const int lane = tid & 63;
  const int wv = __builtin_amdgcn_readfirstlane(tid >> 6);
  const int b = blockIdx.x >> 6;
  const int s0 = (blockIdx.x & 63) * 64;
  const float* xb = x + ((size_t)b * SS + s0) * DD;

  const int r15 = lane & 15;      // A row within tile / B,D col
  const int kg = lane >> 4;       // k-group
  const int arow = wv * 16 + r15; // row in 64-row block

  const int str = tid >> 5;       // staging row (2 rows per wave-load)
  const int stc = (tid & 31) * 4; // staging col (float4)

  f32x4 acc = {0.f, 0.f, 0.f, 0.f};
  float4 st[8];

  // prologue: load chunk 0
#pragma unroll
  for (int k = 0; k < 8; ++k)
    st[k] = *reinterpret_cast<const float4*>(xb + (size_t)(str + k * 8) * DD + stc);
#pragma unroll
  for (int k = 0; k < 8; ++k)
    *reinterpret_cast<float4*>(&xt[(str + k * 8) * XSTRIDE + stc]) = st[k];
  __syncthreads();

  for (int c = 0; c < 8; ++c) {
    // T14: issue next chunk's global loads before compute
    if (c < 7) {
#pragma unroll
      for (int k = 0; k < 8; ++k)
        st[k] = *reinterpret_cast<const float4*>(
            xb + (size_t)(str + k * 8) * DD + (c + 1) * 128 + stc);
    }

    // compute chunk c: 4 K-steps of 32
#pragma unroll
    for (int t4 = 0; t4 < 4; ++t4) {
      const int t = c * 4 + t4;
      // A frag: 8 consecutive fp32 from LDS (k = t4*32 + kg*8 + e)
      const float* xp = &xt[arow * XSTRIDE + t4 * 32 + kg * 8];
      float4 va = *reinterpret_cast<const float4*>(xp);
      float4 vb = *reinterpret_cast<const float4*>(xp + 4);
      float xv[8] = {va.x, va.y, va.z, va.w, vb.x, vb.y, vb.z, vb.w};
      short8 ahi, alo;
#pragma unroll
      for (int e = 0; e < 8; ++e) {
        unsigned bits = __float_as_uint(xv[e]);
        ahi[e] = (short)(bits >> 16);
        float hf = __uint_as_float(bits & 0xffff0000u);
        alo[e] = (short)bf16_rne(xv[e] - hf);
      }
      // B frags: 16B coalesced loads, L2-resident
      short8 bh = *reinterpret_cast<const short8*>(whi + ((size_t)t * 64 + lane) * 8);
      short8 bl = *reinterpret_cast<const short8*>(wlo + ((size_t)t * 64 + lane) * 8);
      acc = __builtin_amdgcn_mfma_f32_16x16x32_bf16(ahi, bh, acc, 0, 0, 0);
      acc = __builtin_amdgcn_mfma_f32_16x16x32_bf16(ahi, bl, acc, 0, 0, 0);
      acc = __builtin_amdgcn_mfma_f32_16x16x32_bf16(alo, bh, acc, 0, 0, 0);
    }
    __syncthreads();  // all waves done reading xt
    if (c < 7) {
#pragma unroll
      for (int k = 0; k < 8; ++k)
        *reinterpret_cast<float4*>(&xt[(str + k * 8) * XSTRIDE + stc]) = st[k];
      __syncthreads();
    }
  }

  // epilogue: D tile row = kg*4 + q, col = r15 (m89-verified layout)
#pragma unroll
  for (int q = 0; q < 4; ++q) {
    int srow = s0 + wv * 16 + kg * 4 + q;
    float v = acc[q] * 0.125f;  // 1/sqrt(64)
    int m = mask[b * SS + srow];
    logits[((size_t)b * SS + srow) * HH + r15] = m ? v : -INFINITY;
  }
}

__device__ __forceinline__ float wave_max64(float v) {
#pragma unroll
  for (int off = 32; off > 0; off >>= 1) v = fmaxf(v, __shfl_xor(v, off, 64));
  return v;
}
__device__ __forceinline__ float wave_sum64(float v) {
#pragma unroll
  for (int off = 32; off > 0; off >>= 1) v += __shfl_xor(v, off, 64);
  return v;
}

// K2: per (b,h) masked softmax over S=4096, normalize in place.
__global__ __launch_bounds__(256) void k_softmax(float* __restrict__ logits) {
  __shared__ float sred[4];
  const int tid = threadIdx.x;
  const int lane = tid & 63;
  const int wv = tid >> 6;
  const int b = blockIdx.x >> 4;
  const int h = blockIdx.x & 15;
  float* base = logits + (size_t)b * SS * HH + h;

  float v[16];
  float m = -INFINITY;
#pragma unroll
  for (int k = 0; k < 16; ++k) {
    v[k] = base[(size_t)(k * 256 + tid) * HH];
    m = fmaxf(m, v[k]);
  }
  m = wave_max64(m);
  if (lane == 0) sred[wv] = m;
  __syncthreads();
  m = fmaxf(fmaxf(sred[0], sred[1]), fmaxf(sred[2], sred[3]));
  __syncthreads();

  float ssum = 0.f;
#pragma unroll
  for (int k = 0; k < 16; ++k) {
    v[k] = __expf(v[k] - m);
    ssum += v[k];
  }
  ssum = wave_sum64(ssum);
  if (lane == 0) sred[wv] = ssum;
  __syncthreads();
  float inv = 1.0f / (sred[0] + sred[1] + sred[2] + sred[3]);
#pragma unroll
  for (int k = 0; k < 16; ++k) base[(size_t)(k * 256 + tid) * HH] = v[k] * inv;
}

// K3: pooling partials. grid 256 (= 8 b * 32 s-chunks of 128 rows), block 256.
__global__ __launch_bounds__(256) void k_pool(
    const float* __restrict__ x, const float* __restrict__ wn,
    float* __restrict__ partial) {
  __shared__ float wl[128][16];
  const int tid = threadIdx.x;
  const int b = blockIdx.x >> 5;
  const int sc = blockIdx.x & 31;
  const int s0 = sc * 128;

#pragma unroll
  for (int k = 0; k < 2; ++k) {
    int f = k * 256 + tid;
    float4 v = *reinterpret_cast<const float4*>(wn + ((size_t)b * SS + s0) * HH + f * 4);
    *reinterpret_cast<float4*>(&wl[0][0] + f * 4) = v;
  }
  __syncthreads();

  float4 acc[HH];
#pragma unroll
  for (int h = 0; h < HH; ++h) acc[h] = make_float4(0.f, 0.f, 0.f, 0.f);

  const float* xb = x + ((size_t)b * SS + s0) * DD + tid * 4;
  for (int s = 0; s < 128; ++s) {
    float4 xv = *reinterpret_cast<const float4*>(xb + (size_t)s * DD);
    const float4* wrow = reinterpret_cast<const float4*>(wl[s]);
    float4 wa = wrow[0], wb_ = wrow[1], wc = wrow[2], wd = wrow[3];
    float wvv[16] = {wa.x, wa.y, wa.z, wa.w, wb_.x, wb_.y, wb_.z, wb_.w,
                     wc.x, wc.y, wc.z, wc.w, wd.x, wd.y, wd.z, wd.w};
#pragma unroll
    for (int h = 0; h < HH; ++h) {
      float w = wvv[h];
      acc[h].x += w * xv.x; acc[h].y += w * xv.y;
      acc[h].z += w * xv.z; acc[h].w += w * xv.w;
    }
  }

  float* pb = partial + ((size_t)sc * BB + b) * (HH * DD) + tid * 4;
#pragma unroll
  for (int h = 0; h < HH; ++h)
    *reinterpret_cast<float4*>(pb + (size_t)h * DD) = acc[h];
}

// K4: reduce 32 s-chunk partials. grid 512, block 256.
__global__ __launch_bounds__(256) void k_reduce(
    const float* __restrict__ partial, float* __restrict__ out) {
  const int idx = blockIdx.x * 256 + threadIdx.x;
  float s = 0.f;
#pragma unroll
  for (int c = 0; c < 32; ++c) s += partial[(size_t)c * (BB * HH * DD) + idx];
  out[idx] = s;
}

extern "C" void kernel_launch(void* const* d_in, const int* in_sizes, int n_in,
                              void* d_out, int out_size, void* d_ws, size_t ws_size,
                              hipStream_t stream) {
  const float* x = (const float*)d_in[0];     // [8][4096][1024] fp32
  const float* W = (const float*)d_in[1];     // [1024][16] fp32
  const int* mask = (const int*)d_in[2];      // [8][4096] int32
  float* out = (float*)d_out;                 // [8][16384] fp32

  float* logits = (float*)d_ws;                                      // 2 MB
  char* p2 = (char*)d_ws + (size_t)BB * SS * HH * 4;
  float* partial = (float*)p2;                                       // 16 MB
  ushort* whi = (ushort*)p2;                                         // alias (K0/K1 only)
  ushort* wlo = (ushort*)(p2 + 32 * 1024);

  k_prepw<<<64, 256, 0, stream>>>(W, whi, wlo);
  k_logits<<<512, 256, 0, stream>>>(x, whi, wlo, mask, logits);
  k_softmax<<<128, 256, 0, stream>>>(logits);
  k_pool<<<256, 256, 0, stream>>>(x, logits, partial);
  k_reduce<<<512, 256, 0, stream>>>(partial, out);
}

// Round 3
// 98.393 us; speedup vs baseline: 1.2814x; 1.2814x over previous
//
#include <hip/hip_runtime.h>
#include <math.h>

#define BB 8
#define SS 4096
#define DD 1024
#define HH 16

typedef __attribute__((ext_vector_type(8))) short short8;
typedef __attribute__((ext_vector_type(4))) float f32x4;

// ws layout (no aliasing):
//   plog    [2][BB][SS][HH] fp32 = 4 MB   @ 0        (K-half partial logits)
//   wbuf    [BB][SS][HH]    fp32 = 2 MB   @ 4 MB     (normalized weights)
//   partial [32][BB][HH][DD]fp32 = 16 MB  @ 6 MB
//   whi/wlo frag streams 32+32 KB         @ 22 MB

__device__ __forceinline__ ushort bf16_rne(float f) {
  unsigned b = __float_as_uint(f);
  return (ushort)((b + 0x7fffu + ((b >> 16) & 1u)) >> 16);
}

// K0: W frag streams. Element e of lane l at global K-step t <-> k = t*32+(l>>4)*8+e,
// col h = l&15. Layout [t][lane][e] ushort, t = 0..31.
__global__ __launch_bounds__(256) void k_prepw(
    const float* __restrict__ W, ushort* __restrict__ whi, ushort* __restrict__ wlo) {
  int i = blockIdx.x * 256 + threadIdx.x;  // 16384
  int t = i >> 9;
  int l = (i >> 3) & 63;
  int e = i & 7;
  int d = t * 32 + (l >> 4) * 8 + e;
  int h = l & 15;
  float w = W[d * HH + h];
  unsigned b = __float_as_uint(w);
  whi[i] = (ushort)(b >> 16);
  float hf = __uint_as_float(b & 0xffff0000u);
  wlo[i] = bf16_rne(w - hf);
}

// K1: staging-free MFMA logits. No LDS, no barriers. K split in halves.
// grid 1024 (= 512 s-tiles x 2 k-halves), block 256 = 4 INDEPENDENT waves x 16 rows.
__global__ __launch_bounds__(256, 4) void k_logits(
    const float* __restrict__ x, const ushort* __restrict__ whi,
    const ushort* __restrict__ wlo, float* __restrict__ plog) {
  const int tid = threadIdx.x;
  const int lane = tid & 63;
  const int wv = tid >> 6;
  const int kh = blockIdx.x & 1;
  const int tile = blockIdx.x >> 1;
  const int b = tile >> 6;
  const int s0 = (tile & 63) * 64;
  const int r15 = lane & 15;
  const int kg = lane >> 4;
  const int row = s0 + wv * 16 + r15;

  // A: per t-step the wave reads 16 rows x 128 B contiguous — coalesced.
  const float* xr = x + ((size_t)b * SS + row) * DD + kh * 512 + kg * 8;
  // B: 64 KB stream, L2-resident, same for all waves.
  const short8* bhp = reinterpret_cast<const short8*>(whi) + (kh * 16 * 64 + lane);
  const short8* blp = reinterpret_cast<const short8*>(wlo) + (kh * 16 * 64 + lane);

  f32x4 acc = {0.f, 0.f, 0.f, 0.f};
#pragma unroll 4
  for (int t = 0; t < 16; ++t) {
    float4 va = *reinterpret_cast<const float4*>(xr + t * 32);
    float4 vb = *reinterpret_cast<const float4*>(xr + t * 32 + 4);
    short8 bh = bhp[t * 64];
    short8 bl = blp[t * 64];
    float xv[8] = {va.x, va.y, va.z, va.w, vb.x, vb.y, vb.z, vb.w};
    short8 ahi, alo;
#pragma unroll
    for (int e = 0; e < 8; ++e) {
      unsigned bits = __float_as_uint(xv[e]);
      ahi[e] = (short)(bits >> 16);
      float hf = __uint_as_float(bits & 0xffff0000u);
      alo[e] = (short)bf16_rne(xv[e] - hf);
    }
    acc = __builtin_amdgcn_mfma_f32_16x16x32_bf16(ahi, bh, acc, 0, 0, 0);
    acc = __builtin_amdgcn_mfma_f32_16x16x32_bf16(ahi, bl, acc, 0, 0, 0);
    acc = __builtin_amdgcn_mfma_f32_16x16x32_bf16(alo, bh, acc, 0, 0, 0);
  }

  // D layout: col = r15, row = kg*4+q (m89-verified; same epilogue passed round 2)
  float* ob = plog + (size_t)kh * (BB * SS * HH) +
              ((size_t)b * SS + s0 + wv * 16) * HH;
#pragma unroll
  for (int q = 0; q < 4; ++q)
    ob[(size_t)(kg * 4 + q) * HH + r15] = acc[q];
}

__device__ __forceinline__ float wave_max64(float v) {
#pragma unroll
  for (int off = 32; off > 0; off >>= 1) v = fmaxf(v, __shfl_xor(v, off, 64));
  return v;
}
__device__ __forceinline__ float wave_sum64(float v) {
#pragma unroll
  for (int off = 32; off > 0; off >>= 1) v += __shfl_xor(v, off, 64);
  return v;
}

// K2: combine K-halves, scale, mask, softmax over S per (b,h); write weights.
__global__ __launch_bounds__(256) void k_softmax(
    const float* __restrict__ plog, const int* __restrict__ mask,
    float* __restrict__ wout) {
  __shared__ float sred[4];
  const int tid = threadIdx.x;
  const int lane = tid & 63;
  const int wv = tid >> 6;
  const int b = blockIdx.x >> 4;
  const int h = blockIdx.x & 15;
  const float* b0 = plog + (size_t)b * SS * HH + h;
  const float* b1 = b0 + (size_t)BB * SS * HH;
  const int* mb = mask + b * SS;

  float v[16];
  float m = -INFINITY;
#pragma unroll
  for (int k = 0; k < 16; ++k) {
    int s = k * 256 + tid;
    float lv = (b0[(size_t)s * HH] + b1[(size_t)s * HH]) * 0.125f;
    v[k] = mb[s] ? lv : -INFINITY;
    m = fmaxf(m, v[k]);
  }
  m = wave_max64(m);
  if (lane == 0) sred[wv] = m;
  __syncthreads();
  m = fmaxf(fmaxf(sred[0], sred[1]), fmaxf(sred[2], sred[3]));
  __syncthreads();

  float ssum = 0.f;
#pragma unroll
  for (int k = 0; k < 16; ++k) {
    v[k] = __expf(v[k] - m);
    ssum += v[k];
  }
  ssum = wave_sum64(ssum);
  if (lane == 0) sred[wv] = ssum;
  __syncthreads();
  float inv = 1.0f / (sred[0] + sred[1] + sred[2] + sred[3]);
#pragma unroll
  for (int k = 0; k < 16; ++k) {
    int s = k * 256 + tid;
    wout[((size_t)b * SS + s) * HH + h] = v[k] * inv;
  }
}

// K3: pooling partials. grid 256 (= 8 b x 32 s-chunks of 128 rows), block 256.
__global__ __launch_bounds__(256) void k_pool(
    const float* __restrict__ x, const float* __restrict__ wn,
    float* __restrict__ partial) {
  __shared__ float wl[128][16];
  const int tid = threadIdx.x;
  const int b = blockIdx.x >> 5;
  const int sc = blockIdx.x & 31;
  const int s0 = sc * 128;

#pragma unroll
  for (int k = 0; k < 2; ++k) {
    int f = k * 256 + tid;
    float4 v = *reinterpret_cast<const float4*>(wn + ((size_t)b * SS + s0) * HH + f * 4);
    *reinterpret_cast<float4*>(&wl[0][0] + f * 4) = v;
  }
  __syncthreads();

  float4 acc[HH];
#pragma unroll
  for (int h = 0; h < HH; ++h) acc[h] = make_float4(0.f, 0.f, 0.f, 0.f);

  const float* xb = x + ((size_t)b * SS + s0) * DD + tid * 4;
  for (int s = 0; s < 128; ++s) {
    float4 xv = *reinterpret_cast<const float4*>(xb + (size_t)s * DD);
    const float4* wrow = reinterpret_cast<const float4*>(wl[s]);
    float4 wa = wrow[0], wb_ = wrow[1], wc = wrow[2], wd = wrow[3];
    float wvv[16] = {wa.x, wa.y, wa.z, wa.w, wb_.x, wb_.y, wb_.z, wb_.w,
                     wc.x, wc.y, wc.z, wc.w, wd.x, wd.y, wd.z, wd.w};
#pragma unroll
    for (int h = 0; h < HH; ++h) {
      float w = wvv[h];
      acc[h].x += w * xv.x; acc[h].y += w * xv.y;
      acc[h].z += w * xv.z; acc[h].w += w * xv.w;
    }
  }

  float* pb = partial + ((size_t)sc * BB + b) * (HH * DD) + tid * 4;
#pragma unroll
  for (int h = 0; h < HH; ++h)
    *reinterpret_cast<float4*>(pb + (size_t)h * DD) = acc[h];
}

// K4: reduce 32 s-chunk partials. grid 512, block 256.
__global__ __launch_bounds__(256) void k_reduce(
    const float* __restrict__ partial, float* __restrict__ out) {
  const int idx = blockIdx.x * 256 + threadIdx.x;
  float s = 0.f;
#pragma unroll
  for (int c = 0; c < 32; ++c) s += partial[(size_t)c * (BB * HH * DD) + idx];
  out[idx] = s;
}

extern "C" void kernel_launch(void* const* d_in, const int* in_sizes, int n_in,
                              void* d_out, int out_size, void* d_ws, size_t ws_size,
                              hipStream_t stream) {
  const float* x = (const float*)d_in[0];     // [8][4096][1024] fp32
  const float* W = (const float*)d_in[1];     // [1024][16] fp32
  const int* mask = (const int*)d_in[2];      // [8][4096] int32
  float* out = (float*)d_out;                 // [8][16384] fp32

  char* ws = (char*)d_ws;
  float* plog    = (float*)ws;                                   // 4 MB
  float* wbuf    = (float*)(ws + (size_t)4 * 1024 * 1024);       // 2 MB
  float* partial = (float*)(ws + (size_t)6 * 1024 * 1024);       // 16 MB
  ushort* whi    = (ushort*)(ws + (size_t)22 * 1024 * 1024);     // 32 KB
  ushort* wlo    = (ushort*)(ws + (size_t)22 * 1024 * 1024 + 32 * 1024);

  k_prepw<<<64, 256, 0, stream>>>(W, whi, wlo);
  k_logits<<<1024, 256, 0, stream>>>(x, whi, wlo, plog);
  k_softmax<<<128, 256, 0, stream>>>(plog, mask, wbuf);
  k_pool<<<256, 256, 0, stream>>>(x, wbuf, partial);
  k_reduce<<<512, 256, 0, stream>>>(partial, out);
}

// Round 5
// 98.207 us; speedup vs baseline: 1.2839x; 1.0019x over previous
//
#include <hip/hip_runtime.h>
#include <math.h>

#define BB 8
#define SS 4096
#define DD 1024
#define HH 16

typedef __attribute__((ext_vector_type(4))) float f32x4;
typedef __fp16 fp16x2 __attribute__((ext_vector_type(2)));
typedef _Float16 half8v __attribute__((ext_vector_type(8)));

// ws layout (no aliasing):
//   plog    [2][BB][SS][HH] fp32 = 4 MB   @ 0        (K-half partial logits)
//   wbuf    [BB][SS][HH]    fp32 = 2 MB   @ 4 MB     (normalized weights)
//   partial [32][BB][HH][DD]fp32 = 16 MB  @ 6 MB
//   wh16/wl16 fp16 frag streams 32+32 KB  @ 22 MB

// K0: W fp16 hi/lo frag streams. Element e of lane l at K-step t <-> k =
// t*32 + (l>>4)*8 + e, col h = l&15. Layout [t][lane][e], t = 0..31.
__global__ __launch_bounds__(256) void k_prepw(
    const float* __restrict__ W, ushort* __restrict__ wh16, ushort* __restrict__ wl16) {
  int i = blockIdx.x * 256 + threadIdx.x;  // 16384
  int t = i >> 9;
  int l = (i >> 3) & 63;
  int e = i & 7;
  int d = t * 32 + (l >> 4) * 8 + e;
  int h = l & 15;
  float w = W[d * HH + h];
  _Float16 wh = (_Float16)w;               // RNE
  _Float16 wl = (_Float16)(w - (float)wh); // residual, |wl| <= 2^-11 |w|
  union { _Float16 f; ushort u; } ch, cl;
  ch.f = wh; cl.f = wl;
  wh16[i] = ch.u;
  wl16[i] = cl.u;
}

// K1: staging-free fp16-split MFMA logits. No LDS, no barriers.
// grid 1024 (= 512 s-tiles x 2 k-halves), block 256 = 4 independent waves x 16 rows.
// Per t-step: 2 x-loads + 2 W-loads + 4 v_cvt_pkrtz + 2 MFMA.
__global__ __launch_bounds__(256, 4) void k_logits(
    const float* __restrict__ x, const ushort* __restrict__ wh16,
    const ushort* __restrict__ wl16, float* __restrict__ plog) {
  const int tid = threadIdx.x;
  const int lane = tid & 63;
  const int wv = tid >> 6;
  const int kh = blockIdx.x & 1;
  const int tile = blockIdx.x >> 1;
  const int b = tile >> 6;
  const int s0 = (tile & 63) * 64;
  const int r15 = lane & 15;
  const int kg = lane >> 4;
  const int row = s0 + wv * 16 + r15;

  const float* xr = x + ((size_t)b * SS + row) * DD + kh * 512 + kg * 8;
  const half8v* bhp = reinterpret_cast<const half8v*>(wh16) + (kh * 16 * 64 + lane);
  const half8v* blp = reinterpret_cast<const half8v*>(wl16) + (kh * 16 * 64 + lane);

  f32x4 acch = {0.f, 0.f, 0.f, 0.f};
  f32x4 accl = {0.f, 0.f, 0.f, 0.f};
#pragma unroll 4
  for (int t = 0; t < 16; ++t) {
    float4 va = *reinterpret_cast<const float4*>(xr + t * 32);
    float4 vb = *reinterpret_cast<const float4*>(xr + t * 32 + 4);
    half8v bh = bhp[t * 64];
    half8v bl = blp[t * 64];
    union { fp16x2 h2[4]; half8v h8; } ax;
    ax.h2[0] = __builtin_amdgcn_cvt_pkrtz(va.x, va.y);
    ax.h2[1] = __builtin_amdgcn_cvt_pkrtz(va.z, va.w);
    ax.h2[2] = __builtin_amdgcn_cvt_pkrtz(vb.x, vb.y);
    ax.h2[3] = __builtin_amdgcn_cvt_pkrtz(vb.z, vb.w);
    acch = __builtin_amdgcn_mfma_f32_16x16x32_f16(ax.h8, bh, acch, 0, 0, 0);
    accl = __builtin_amdgcn_mfma_f32_16x16x32_f16(ax.h8, bl, accl, 0, 0, 0);
  }

  // D layout: col = r15, row = kg*4+q (m89-verified; same epilogue passed R2/R3)
  float* ob = plog + (size_t)kh * (BB * SS * HH) +
              ((size_t)b * SS + s0 + wv * 16) * HH;
#pragma unroll
  for (int q = 0; q < 4; ++q)
    ob[(size_t)(kg * 4 + q) * HH + r15] = acch[q] + accl[q];
}

__device__ __forceinline__ float wave_max64(float v) {
#pragma unroll
  for (int off = 32; off > 0; off >>= 1) v = fmaxf(v, __shfl_xor(v, off, 64));
  return v;
}
__device__ __forceinline__ float wave_sum64(float v) {
#pragma unroll
  for (int off = 32; off > 0; off >>= 1) v += __shfl_xor(v, off, 64);
  return v;
}

// K2: combine K-halves, scale, mask, softmax over S per (b,h); write weights.
__global__ __launch_bounds__(256) void k_softmax(
    const float* __restrict__ plog, const int* __restrict__ mask,
    float* __restrict__ wout) {
  __shared__ float sred[4];
  const int tid = threadIdx.x;
  const int lane = tid & 63;
  const int wv = tid >> 6;
  const int b = blockIdx.x >> 4;
  const int h = blockIdx.x & 15;
  const float* b0 = plog + (size_t)b * SS * HH + h;
  const float* b1 = b0 + (size_t)BB * SS * HH;
  const int* mb = mask + b * SS;

  float v[16];
  float m = -INFINITY;
#pragma unroll
  for (int k = 0; k < 16; ++k) {
    int s = k * 256 + tid;
    float lv = (b0[(size_t)s * HH] + b1[(size_t)s * HH]) * 0.125f;
    v[k] = mb[s] ? lv : -INFINITY;
    m = fmaxf(m, v[k]);
  }
  m = wave_max64(m);
  if (lane == 0) sred[wv] = m;
  __syncthreads();
  m = fmaxf(fmaxf(sred[0], sred[1]), fmaxf(sred[2], sred[3]));
  __syncthreads();

  float ssum = 0.f;
#pragma unroll
  for (int k = 0; k < 16; ++k) {
    v[k] = __expf(v[k] - m);
    ssum += v[k];
  }
  ssum = wave_sum64(ssum);
  if (lane == 0) sred[wv] = ssum;
  __syncthreads();
  float inv = 1.0f / (sred[0] + sred[1] + sred[2] + sred[3]);
#pragma unroll
  for (int k = 0; k < 16; ++k) {
    int s = k * 256 + tid;
    wout[((size_t)b * SS + s) * HH + h] = v[k] * inv;
  }
}

// K3: pooling partials. grid 256 (= 8 b x 32 s-chunks of 128 rows), block 256.
__global__ __launch_bounds__(256) void k_pool(
    const float* __restrict__ x, const float* __restrict__ wn,
    float* __restrict__ partial) {
  __shared__ float wl[128][16];
  const int tid = threadIdx.x;
  const int b = blockIdx.x >> 5;
  const int sc = blockIdx.x & 31;
  const int s0 = sc * 128;

#pragma unroll
  for (int k = 0; k < 2; ++k) {
    int f = k * 256 + tid;
    float4 v = *reinterpret_cast<const float4*>(wn + ((size_t)b * SS + s0) * HH + f * 4);
    *reinterpret_cast<float4*>(&wl[0][0] + f * 4) = v;
  }
  __syncthreads();

  float4 acc[HH];
#pragma unroll
  for (int h = 0; h < HH; ++h) acc[h] = make_float4(0.f, 0.f, 0.f, 0.f);

  const float* xb = x + ((size_t)b * SS + s0) * DD + tid * 4;
  for (int s = 0; s < 128; ++s) {
    float4 xv = *reinterpret_cast<const float4*>(xb + (size_t)s * DD);
    const float4* wrow = reinterpret_cast<const float4*>(wl[s]);
    float4 wa = wrow[0], wb_ = wrow[1], wc = wrow[2], wd = wrow[3];
    float wvv[16] = {wa.x, wa.y, wa.z, wa.w, wb_.x, wb_.y, wb_.z, wb_.w,
                     wc.x, wc.y, wc.z, wc.w, wd.x, wd.y, wd.z, wd.w};
#pragma unroll
    for (int h = 0; h < HH; ++h) {
      float w = wvv[h];
      acc[h].x += w * xv.x; acc[h].y += w * xv.y;
      acc[h].z += w * xv.z; acc[h].w += w * xv.w;
    }
  }

  float* pb = partial + ((size_t)sc * BB + b) * (HH * DD) + tid * 4;
#pragma unroll
  for (int h = 0; h < HH; ++h)
    *reinterpret_cast<float4*>(pb + (size_t)h * DD) = acc[h];
}

// K4: reduce 32 s-chunk partials. grid 512, block 256.
__global__ __launch_bounds__(256) void k_reduce(
    const float* __restrict__ partial, float* __restrict__ out) {
  const int idx = blockIdx.x * 256 + threadIdx.x;
  float s = 0.f;
#pragma unroll
  for (int c = 0; c < 32; ++c) s += partial[(size_t)c * (BB * HH * DD) + idx];
  out[idx] = s;
}

extern "C" void kernel_launch(void* const* d_in, const int* in_sizes, int n_in,
                              void* d_out, int out_size, void* d_ws, size_t ws_size,
                              hipStream_t stream) {
  const float* x = (const float*)d_in[0];     // [8][4096][1024] fp32
  const float* W = (const float*)d_in[1];     // [1024][16] fp32
  const int* mask = (const int*)d_in[2];      // [8][4096] int32
  float* out = (float*)d_out;                 // [8][16384] fp32

  char* ws = (char*)d_ws;
  float* plog    = (float*)ws;                                   // 4 MB
  float* wbuf    = (float*)(ws + (size_t)4 * 1024 * 1024);       // 2 MB
  float* partial = (float*)(ws + (size_t)6 * 1024 * 1024);       // 16 MB
  ushort* wh16   = (ushort*)(ws + (size_t)22 * 1024 * 1024);     // 32 KB
  ushort* wl16   = (ushort*)(ws + (size_t)22 * 1024 * 1024 + 32 * 1024);

  k_prepw<<<64, 256, 0, stream>>>(W, wh16, wl16);
  k_logits<<<1024, 256, 0, stream>>>(x, wh16, wl16, plog);
  k_softmax<<<128, 256, 0, stream>>>(plog, mask, wbuf);
  k_pool<<<256, 256, 0, stream>>>(x, wbuf, partial);
  k_reduce<<<512, 256, 0, stream>>>(partial, out);
}

// Round 7
// 80.504 us; speedup vs baseline: 1.5662x; 1.2199x over previous
//
#include <hip/hip_runtime.h>
#include <math.h>

#define BB 8
#define SS 4096
#define DD 1024
#define HH 16

typedef __attribute__((ext_vector_type(4))) float f32x4;
typedef __fp16 fp16x2 __attribute__((ext_vector_type(2)));
typedef _Float16 half8v __attribute__((ext_vector_type(8)));

// ws layout (no aliasing):
//   plog    [2][BB][SS][HH] fp32 = 4 MB   @ 0        (K-half partial logits)
//   wbuf    [BB][SS][HH]    fp32 = 2 MB   @ 4 MB     (normalized weights)
//   partial [32][BB][HH][DD]fp32 = 16 MB  @ 6 MB
//   wh16/wl16 fp16 frag streams 32+32 KB  @ 22 MB

// K0: W fp16 hi/lo frag streams. Element e of lane l at K-step t <-> k =
// t*32 + (l>>4)*8 + e, col h = l&15. Layout [t][lane][e], t = 0..31.
__global__ __launch_bounds__(256) void k_prepw(
    const float* __restrict__ W, ushort* __restrict__ wh16, ushort* __restrict__ wl16) {
  int i = blockIdx.x * 256 + threadIdx.x;  // 16384
  int t = i >> 9;
  int l = (i >> 3) & 63;
  int e = i & 7;
  int d = t * 32 + (l >> 4) * 8 + e;
  int h = l & 15;
  float w = W[d * HH + h];
  _Float16 wh = (_Float16)w;               // RNE
  _Float16 wl = (_Float16)(w - (float)wh); // residual, |wl| <= 2^-11 |w|
  union { _Float16 f; ushort u; } ch, cl;
  ch.f = wh; cl.f = wl;
  wh16[i] = ch.u;
  wl16[i] = cl.u;
}

// K1 v3: LDS-transposed fp16-split MFMA logits. CONTIGUOUS global loads
// (4 rows x 256 B per instruction), wave-private LDS staging -> NO barriers.
// grid 1024 (= 512 s-tiles x 2 k-halves), block 256 = 4 independent waves.
// Per chunk (64 floats of K): 4 global float4 loads -> 4 swizzled ds_write_b128
// -> 2 t-steps x (2 ds_read_b128 + 2 W loads + 4 cvt + 2 MFMA). Double-buffered.
__global__ __launch_bounds__(256, 4) void k_logits(
    const float* __restrict__ x, const ushort* __restrict__ wh16,
    const ushort* __restrict__ wl16, float* __restrict__ plog) {
  // [buf][wave][row][unit] : 2*4*16*16 float4 = 32 KB, wave-private slices
  __shared__ float4 lds4[2][4][16][16];

  const int tid = threadIdx.x;
  const int lane = tid & 63;
  const int wv = tid >> 6;
  const int kh = blockIdx.x & 1;
  const int tile = blockIdx.x >> 1;
  const int b = tile >> 6;
  const int s0 = (tile & 63) * 64;
  const int r15 = lane & 15;      // A row within wave tile / D col
  const int kg = lane >> 4;       // k-group
  const int srow = lane >> 4;     // staging sub-row
  const int sul = lane & 15;      // staging unit (16 B)

  // wave's 16 rows start here; k-range [kh*512, kh*512+512)
  const float* xw = x + ((size_t)b * SS + s0 + wv * 16) * DD + kh * 512;
  // bhp/blp are ALREADY offset by the K-half; index with LOCAL t below.
  const half8v* bhp = reinterpret_cast<const half8v*>(wh16) + (kh * 16 * 64 + lane);
  const half8v* blp = reinterpret_cast<const half8v*>(wl16) + (kh * 16 * 64 + lane);

  f32x4 acch = {0.f, 0.f, 0.f, 0.f};
  f32x4 accl = {0.f, 0.f, 0.f, 0.f};

  float4 st[4];
  // prologue: load + stage chunk 0
#pragma unroll
  for (int k = 0; k < 4; ++k) {
    int row = k * 4 + srow;
    st[k] = *reinterpret_cast<const float4*>(xw + (size_t)row * DD + sul * 4);
  }
#pragma unroll
  for (int k = 0; k < 4; ++k) {
    int row = k * 4 + srow;
    lds4[0][wv][row][sul ^ (row & 7)] = st[k];
  }

#pragma unroll
  for (int c = 0; c < 8; ++c) {
    // T14 issue-early: next chunk's global loads before compute
    if (c < 7) {
#pragma unroll
      for (int k = 0; k < 4; ++k) {
        int row = k * 4 + srow;
        st[k] = *reinterpret_cast<const float4*>(
            xw + (size_t)row * DD + (c + 1) * 64 + sul * 4);
      }
    }

    // compute chunk c from buf c&1 (wave-private -> no barrier)
#pragma unroll
    for (int t4 = 0; t4 < 2; ++t4) {
      const int t = c * 2 + t4;  // LOCAL t within this K-half (bug fix vs R6)
      half8v bh = bhp[t * 64];
      half8v bl = blp[t * 64];
      const int u0 = t4 * 8 + kg * 2;
      float4 va = lds4[c & 1][wv][r15][u0 ^ (r15 & 7)];
      float4 vb = lds4[c & 1][wv][r15][(u0 + 1) ^ (r15 & 7)];
      union { fp16x2 h2[4]; half8v h8; } ax;
      ax.h2[0] = __builtin_amdgcn_cvt_pkrtz(va.x, va.y);
      ax.h2[1] = __builtin_amdgcn_cvt_pkrtz(va.z, va.w);
      ax.h2[2] = __builtin_amdgcn_cvt_pkrtz(vb.x, vb.y);
      ax.h2[3] = __builtin_amdgcn_cvt_pkrtz(vb.z, vb.w);
      acch = __builtin_amdgcn_mfma_f32_16x16x32_f16(ax.h8, bh, acch, 0, 0, 0);
      accl = __builtin_amdgcn_mfma_f32_16x16x32_f16(ax.h8, bl, accl, 0, 0, 0);
    }

    // write-late: stage chunk c+1 into the other buffer
    if (c < 7) {
#pragma unroll
      for (int k = 0; k < 4; ++k) {
        int row = k * 4 + srow;
        lds4[(c + 1) & 1][wv][row][sul ^ (row & 7)] = st[k];
      }
    }
  }

  // D layout: col = r15, row = kg*4+q (m89-verified; passed R2/R3/R5)
  float* ob = plog + (size_t)kh * (BB * SS * HH) +
              ((size_t)b * SS + s0 + wv * 16) * HH;
#pragma unroll
  for (int q = 0; q < 4; ++q)
    ob[(size_t)(kg * 4 + q) * HH + r15] = acch[q] + accl[q];
}

__device__ __forceinline__ float wave_max64(float v) {
#pragma unroll
  for (int off = 32; off > 0; off >>= 1) v = fmaxf(v, __shfl_xor(v, off, 64));
  return v;
}
__device__ __forceinline__ float wave_sum64(float v) {
#pragma unroll
  for (int off = 32; off > 0; off >>= 1) v += __shfl_xor(v, off, 64);
  return v;
}

// K2: combine K-halves, scale, mask, softmax over S per (b,h); write weights.
__global__ __launch_bounds__(256) void k_softmax(
    const float* __restrict__ plog, const int* __restrict__ mask,
    float* __restrict__ wout) {
  __shared__ float sred[4];
  const int tid = threadIdx.x;
  const int lane = tid & 63;
  const int wv = tid >> 6;
  const int b = blockIdx.x >> 4;
  const int h = blockIdx.x & 15;
  const float* b0 = plog + (size_t)b * SS * HH + h;
  const float* b1 = b0 + (size_t)BB * SS * HH;
  const int* mb = mask + b * SS;

  float v[16];
  float m = -INFINITY;
#pragma unroll
  for (int k = 0; k < 16; ++k) {
    int s = k * 256 + tid;
    float lv = (b0[(size_t)s * HH] + b1[(size_t)s * HH]) * 0.125f;
    v[k] = mb[s] ? lv : -INFINITY;
    m = fmaxf(m, v[k]);
  }
  m = wave_max64(m);
  if (lane == 0) sred[wv] = m;
  __syncthreads();
  m = fmaxf(fmaxf(sred[0], sred[1]), fmaxf(sred[2], sred[3]));
  __syncthreads();

  float ssum = 0.f;
#pragma unroll
  for (int k = 0; k < 16; ++k) {
    v[k] = __expf(v[k] - m);
    ssum += v[k];
  }
  ssum = wave_sum64(ssum);
  if (lane == 0) sred[wv] = ssum;
  __syncthreads();
  float inv = 1.0f / (sred[0] + sred[1] + sred[2] + sred[3]);
#pragma unroll
  for (int k = 0; k < 16; ++k) {
    int s = k * 256 + tid;
    wout[((size_t)b * SS + s) * HH + h] = v[k] * inv;
  }
}

// K3: pooling partials, D split in half for 2x occupancy (2 waves/SIMD).
// grid 512 (= 8 b x 32 s-chunks x 2 d-halves), block 256; thread owns 2 d.
__global__ __launch_bounds__(256) void k_pool(
    const float* __restrict__ x, const float* __restrict__ wn,
    float* __restrict__ partial) {
  __shared__ float wl[128][16];
  const int tid = threadIdx.x;
  const int dh = blockIdx.x & 1;
  const int sc = (blockIdx.x >> 1) & 31;
  const int b = blockIdx.x >> 6;
  const int s0 = sc * 128;

#pragma unroll
  for (int k = 0; k < 2; ++k) {
    int f = k * 256 + tid;
    float4 v = *reinterpret_cast<const float4*>(wn + ((size_t)b * SS + s0) * HH + f * 4);
    *reinterpret_cast<float4*>(&wl[0][0] + f * 4) = v;
  }
  __syncthreads();

  float2 acc[HH];
#pragma unroll
  for (int h = 0; h < HH; ++h) acc[h] = make_float2(0.f, 0.f);

  const float* xb = x + ((size_t)b * SS + s0) * DD + dh * 512 + tid * 2;
  for (int s = 0; s < 128; ++s) {
    float2 xv = *reinterpret_cast<const float2*>(xb + (size_t)s * DD);
    const float4* wrow = reinterpret_cast<const float4*>(wl[s]);
    float4 wa = wrow[0], wb_ = wrow[1], wc = wrow[2], wd = wrow[3];
    float wvv[16] = {wa.x, wa.y, wa.z, wa.w, wb_.x, wb_.y, wb_.z, wb_.w,
                     wc.x, wc.y, wc.z, wc.w, wd.x, wd.y, wd.z, wd.w};
#pragma unroll
    for (int h = 0; h < HH; ++h) {
      float w = wvv[h];
      acc[h].x += w * xv.x;
      acc[h].y += w * xv.y;
    }
  }

  float* pb = partial + ((size_t)sc * BB + b) * (HH * DD) + dh * 512 + tid * 2;
#pragma unroll
  for (int h = 0; h < HH; ++h)
    *reinterpret_cast<float2*>(pb + (size_t)h * DD) = acc[h];
}

// K4: reduce 32 s-chunk partials. grid 512, block 256.
__global__ __launch_bounds__(256) void k_reduce(
    const float* __restrict__ partial, float* __restrict__ out) {
  const int idx = blockIdx.x * 256 + threadIdx.x;
  float s = 0.f;
#pragma unroll
  for (int c = 0; c < 32; ++c) s += partial[(size_t)c * (BB * HH * DD) + idx];
  out[idx] = s;
}

extern "C" void kernel_launch(void* const* d_in, const int* in_sizes, int n_in,
                              void* d_out, int out_size, void* d_ws, size_t ws_size,
                              hipStream_t stream) {
  const float* x = (const float*)d_in[0];     // [8][4096][1024] fp32
  const float* W = (const float*)d_in[1];     // [1024][16] fp32
  const int* mask = (const int*)d_in[2];      // [8][4096] int32
  float* out = (float*)d_out;                 // [8][16384] fp32

  char* ws = (char*)d_ws;
  float* plog    = (float*)ws;                                   // 4 MB
  float* wbuf    = (float*)(ws + (size_t)4 * 1024 * 1024);       // 2 MB
  float* partial = (float*)(ws + (size_t)6 * 1024 * 1024);       // 16 MB
  ushort* wh16   = (ushort*)(ws + (size_t)22 * 1024 * 1024);     // 32 KB
  ushort* wl16   = (ushort*)(ws + (size_t)22 * 1024 * 1024 + 32 * 1024);

  k_prepw<<<64, 256, 0, stream>>>(W, wh16, wl16);
  k_logits<<<1024, 256, 0, stream>>>(x, wh16, wl16, plog);
  k_softmax<<<128, 256, 0, stream>>>(plog, mask, wbuf);
  k_pool<<<512, 256, 0, stream>>>(x, wbuf, partial);
  k_reduce<<<512, 256, 0, stream>>>(partial, out);
}

// Round 8
// 74.961 us; speedup vs baseline: 1.6820x; 1.0740x over previous
//
#include <hip/hip_runtime.h>
#include <math.h>

#define BB 8
#define SS 4096
#define DD 1024
#define HH 16

typedef __attribute__((ext_vector_type(4))) float f32x4;
typedef __fp16 fp16x2 __attribute__((ext_vector_type(2)));
typedef _Float16 half8v __attribute__((ext_vector_type(8)));

// ws layout (no aliasing):
//   plog    [2][BB][SS][HH] fp32 = 4 MB   @ 0      (K-half partial logits)
//   partial [32][BB][HH][DD]fp32 = 16 MB  @ 6 MB
//   wh16/wl16 fp16 frag streams 32+32 KB  @ 22 MB
//   bred    [BB][32][HH] float2  = 32 KB  @ 23 MB  (per-chunk softmax partials)

// online-softmax merge: (m,z) <- (m,z) ⊕ (om,oz)
__device__ __forceinline__ void sm_merge(float& m, float& z, float om, float oz) {
  float nm = fmaxf(m, om);
  if (nm > -INFINITY)
    z = z * __expf(m - nm) + oz * __expf(om - nm);
  m = nm;
}

// K0: W fp16 hi/lo frag streams. Element e of lane l at K-step t <-> k =
// t*32 + (l>>4)*8 + e, col h = l&15. Layout [t][lane][e], t = 0..31.
__global__ __launch_bounds__(256) void k_prepw(
    const float* __restrict__ W, ushort* __restrict__ wh16, ushort* __restrict__ wl16) {
  int i = blockIdx.x * 256 + threadIdx.x;  // 16384
  int t = i >> 9;
  int l = (i >> 3) & 63;
  int e = i & 7;
  int d = t * 32 + (l >> 4) * 8 + e;
  int h = l & 15;
  float w = W[d * HH + h];
  _Float16 wh = (_Float16)w;               // RNE
  _Float16 wl = (_Float16)(w - (float)wh); // residual, |wl| <= 2^-11 |w|
  union { _Float16 f; ushort u; } ch, cl;
  ch.f = wh; cl.f = wl;
  wh16[i] = ch.u;
  wl16[i] = cl.u;
}

// K1 v4: LDS-transposed fp16-split MFMA logits; 2-chunk-deep x prefetch,
// 1-chunk-ahead W-frag register prefetch. Wave-private LDS -> no barriers.
// grid 1024 (= 512 s-tiles x 2 k-halves), block 256 = 4 independent waves.
__global__ __launch_bounds__(256, 4) void k_logits(
    const float* __restrict__ x, const ushort* __restrict__ wh16,
    const ushort* __restrict__ wl16, float* __restrict__ plog) {
  __shared__ float4 lds4[2][4][16][16];  // [buf][wave][row][unit], 32 KB

  const int tid = threadIdx.x;
  const int lane = tid & 63;
  const int wv = tid >> 6;
  const int kh = blockIdx.x & 1;
  const int tile = blockIdx.x >> 1;
  const int b = tile >> 6;
  const int s0 = (tile & 63) * 64;
  const int r15 = lane & 15;      // A row within wave tile / D col
  const int kg = lane >> 4;       // k-group
  const int srow = lane >> 4;     // staging sub-row
  const int sul = lane & 15;      // staging unit (16 B)

  const float* xw = x + ((size_t)b * SS + s0 + wv * 16) * DD + kh * 512;
  // Offset by K-half here; indexed with LOCAL t (= 2c+j) below.
  const half8v* bhp = reinterpret_cast<const half8v*>(wh16) + (kh * 16 * 64 + lane);
  const half8v* blp = reinterpret_cast<const half8v*>(wl16) + (kh * 16 * 64 + lane);

  f32x4 acch = {0.f, 0.f, 0.f, 0.f};
  f32x4 accl = {0.f, 0.f, 0.f, 0.f};

  float4 stA[4], stB[4];
  half8v whc[2], wlc[2], whn[2], wln[2];

  // prologue: x chunk0 -> stA; W chunk0 -> whc/wlc; stage chunk0; x chunk1 -> stB
#pragma unroll
  for (int k = 0; k < 4; ++k) {
    int row = k * 4 + srow;
    stA[k] = *reinterpret_cast<const float4*>(xw + (size_t)row * DD + sul * 4);
  }
#pragma unroll
  for (int j = 0; j < 2; ++j) { whc[j] = bhp[j * 64]; wlc[j] = blp[j * 64]; }
#pragma unroll
  for (int k = 0; k < 4; ++k) {
    int row = k * 4 + srow;
    lds4[0][wv][row][sul ^ (row & 7)] = stA[k];
  }
#pragma unroll
  for (int k = 0; k < 4; ++k) {
    int row = k * 4 + srow;
    stB[k] = *reinterpret_cast<const float4*>(xw + (size_t)row * DD + 64 + sul * 4);
  }

#pragma unroll
  for (int c = 0; c < 8; ++c) {
    // issue x loads for chunk c+2 (2-deep pipeline)
    if (c < 6) {
      float4* stN = ((c & 1) == 0) ? stA : stB;  // chunk n -> (n&1)?stB:stA
#pragma unroll
      for (int k = 0; k < 4; ++k) {
        int row = k * 4 + srow;
        stN[k] = *reinterpret_cast<const float4*>(
            xw + (size_t)row * DD + (c + 2) * 64 + sul * 4);
      }
    }
    // W-frag prefetch for chunk c+1
    if (c < 7) {
#pragma unroll
      for (int j = 0; j < 2; ++j) {
        whn[j] = bhp[((c + 1) * 2 + j) * 64];
        wln[j] = blp[((c + 1) * 2 + j) * 64];
      }
    }

    // compute chunk c from buf c&1 (wave-private -> no barrier)
#pragma unroll
    for (int t4 = 0; t4 < 2; ++t4) {
      const int u0 = t4 * 8 + kg * 2;
      float4 va = lds4[c & 1][wv][r15][u0 ^ (r15 & 7)];
      float4 vb = lds4[c & 1][wv][r15][(u0 + 1) ^ (r15 & 7)];
      union { fp16x2 h2[4]; half8v h8; } ax;
      ax.h2[0] = __builtin_amdgcn_cvt_pkrtz(va.x, va.y);
      ax.h2[1] = __builtin_amdgcn_cvt_pkrtz(va.z, va.w);
      ax.h2[2] = __builtin_amdgcn_cvt_pkrtz(vb.x, vb.y);
      ax.h2[3] = __builtin_amdgcn_cvt_pkrtz(vb.z, vb.w);
      acch = __builtin_amdgcn_mfma_f32_16x16x32_f16(ax.h8, whc[t4], acch, 0, 0, 0);
      accl = __builtin_amdgcn_mfma_f32_16x16x32_f16(ax.h8, wlc[t4], accl, 0, 0, 0);
    }

    // write-late: stage chunk c+1 (its loads were issued a full chunk ago)
    if (c < 7) {
      float4* stW = (((c + 1) & 1) == 0) ? stA : stB;
#pragma unroll
      for (int k = 0; k < 4; ++k) {
        int row = k * 4 + srow;
        lds4[(c + 1) & 1][wv][row][sul ^ (row & 7)] = stW[k];
      }
      whc[0] = whn[0]; whc[1] = whn[1];
      wlc[0] = wln[0]; wlc[1] = wln[1];
    }
  }

  // D layout: col = r15, row = kg*4+q (m89-verified; passed R2/R3/R5/R7)
  float* ob = plog + (size_t)kh * (BB * SS * HH) +
              ((size_t)b * SS + s0 + wv * 16) * HH;
#pragma unroll
  for (int q = 0; q < 4; ++q)
    ob[(size_t)(kg * 4 + q) * HH + r15] = acch[q] + accl[q];
}

// K2: per (b, 128-row s-chunk) online-softmax partials (m, Z) per h.
// grid 256 (= 8 b x 32 chunks), block 256. Coalesced float4 reads of plog.
__global__ __launch_bounds__(256) void k_smpart(
    const float* __restrict__ plog, const int* __restrict__ mask,
    float2* __restrict__ bred) {  // bred[BB][32][HH]
  __shared__ float4 smm[4][4], smz[4][4];
  const int tid = threadIdx.x;
  const int lane = tid & 63;
  const int wv = tid >> 6;
  const int b = blockIdx.x >> 5;
  const int sc = blockIdx.x & 31;
  const int s0 = sc * 128;
  const float4* p0 = reinterpret_cast<const float4*>(plog + ((size_t)b * SS + s0) * HH);
  const float4* p1 = reinterpret_cast<const float4*>(
      plog + (size_t)BB * SS * HH + ((size_t)b * SS + s0) * HH);
  const int* mb = mask + b * SS + s0;

  // per-thread h-group = tid&3 (h = hg*4+j); 2 float4s per thread, 512 total
  float m4[4] = {-INFINITY, -INFINITY, -INFINITY, -INFINITY};
  float z4[4] = {0.f, 0.f, 0.f, 0.f};
#pragma unroll
  for (int i = 0; i < 2; ++i) {
    int f = i * 256 + tid;
    float4 va = p0[f];
    float4 vb = p1[f];
    int msk = mb[f >> 2];
    float lv[4] = {(va.x + vb.x) * 0.125f, (va.y + vb.y) * 0.125f,
                   (va.z + vb.z) * 0.125f, (va.w + vb.w) * 0.125f};
#pragma unroll
    for (int j = 0; j < 4; ++j) {
      float v = msk ? lv[j] : -INFINITY;
      sm_merge(m4[j], z4[j], v, 1.0f);
    }
  }
  // wave reduce across lanes with equal (lane&3)
#pragma unroll
  for (int off = 4; off < 64; off <<= 1) {
#pragma unroll
    for (int j = 0; j < 4; ++j) {
      float om = __shfl_xor(m4[j], off, 64);
      float oz = __shfl_xor(z4[j], off, 64);
      sm_merge(m4[j], z4[j], om, oz);
    }
  }
  if (lane < 4) {
    smm[wv][lane] = make_float4(m4[0], m4[1], m4[2], m4[3]);
    smz[wv][lane] = make_float4(z4[0], z4[1], z4[2], z4[3]);
  }
  __syncthreads();
  if (tid < 4) {
    float4 mm = smm[0][tid], zz = smz[0][tid];
    float fm[4] = {mm.x, mm.y, mm.z, mm.w};
    float fz[4] = {zz.x, zz.y, zz.z, zz.w};
#pragma unroll
    for (int w = 1; w < 4; ++w) {
      float4 om4 = smm[w][tid], oz4 = smz[w][tid];
      float om[4] = {om4.x, om4.y, om4.z, om4.w};
      float oz[4] = {oz4.x, oz4.y, oz4.z, oz4.w};
#pragma unroll
      for (int j = 0; j < 4; ++j) sm_merge(fm[j], fz[j], om[j], oz[j]);
    }
#pragma unroll
    for (int j = 0; j < 4; ++j)
      bred[((size_t)b * 32 + sc) * HH + tid * 4 + j] = make_float2(fm[j], fz[j]);
  }
}

// K3: pooling with inline softmax finalize. grid 512 (= 8 b x 32 sc x 2 dh),
// block 256; thread owns 2 d. Merges all 32 chunk-partials (16 thr), then
// stages normalized weights wl[s][h] = exp(l - m) / Z, masked -> 0.
__global__ __launch_bounds__(256) void k_pool(
    const float* __restrict__ x, const float* __restrict__ plog,
    const float2* __restrict__ bred, const int* __restrict__ mask,
    float* __restrict__ partial) {
  __shared__ float wl[128][16];
  __shared__ float fm[16], fz[16];
  const int tid = threadIdx.x;
  const int dh = blockIdx.x & 1;
  const int sc = (blockIdx.x >> 1) & 31;
  const int b = blockIdx.x >> 6;
  const int s0 = sc * 128;

  if (tid < 16) {
    float m = -INFINITY, z = 0.f;
#pragma unroll 4
    for (int c = 0; c < 32; ++c) {
      float2 p = bred[((size_t)b * 32 + c) * HH + tid];
      sm_merge(m, z, p.x, p.y);
    }
    fm[tid] = m;
    fz[tid] = (z > 0.f) ? 1.0f / z : 0.f;
  }
  __syncthreads();

  const float4* p0 = reinterpret_cast<const float4*>(plog + ((size_t)b * SS + s0) * HH);
  const float4* p1 = reinterpret_cast<const float4*>(
      plog + (size_t)BB * SS * HH + ((size_t)b * SS + s0) * HH);
  const int* mb = mask + b * SS + s0;
#pragma unroll
  for (int k = 0; k < 2; ++k) {
    int f = k * 256 + tid;  // float4 over [128][16]
    float4 va = p0[f];
    float4 vb = p1[f];
    int msk = mb[f >> 2];
    int hb = (f & 3) * 4;
    float4 w;
    w.x = msk ? __expf((va.x + vb.x) * 0.125f - fm[hb + 0]) * fz[hb + 0] : 0.f;
    w.y = msk ? __expf((va.y + vb.y) * 0.125f - fm[hb + 1]) * fz[hb + 1] : 0.f;
    w.z = msk ? __expf((va.z + vb.z) * 0.125f - fm[hb + 2]) * fz[hb + 2] : 0.f;
    w.w = msk ? __expf((va.w + vb.w) * 0.125f - fm[hb + 3]) * fz[hb + 3] : 0.f;
    *reinterpret_cast<float4*>(&wl[0][0] + f * 4) = w;
  }
  __syncthreads();

  float2 acc[HH];
#pragma unroll
  for (int h = 0; h < HH; ++h) acc[h] = make_float2(0.f, 0.f);

  const float* xb = x + ((size_t)b * SS + s0) * DD + dh * 512 + tid * 2;
  for (int s = 0; s < 128; ++s) {
    float2 xv = *reinterpret_cast<const float2*>(xb + (size_t)s * DD);
    const float4* wrow = reinterpret_cast<const float4*>(wl[s]);
    float4 wa = wrow[0], wb_ = wrow[1], wc = wrow[2], wd = wrow[3];
    float wvv[16] = {wa.x, wa.y, wa.z, wa.w, wb_.x, wb_.y, wb_.z, wb_.w,
                     wc.x, wc.y, wc.z, wc.w, wd.x, wd.y, wd.z, wd.w};
#pragma unroll
    for (int h = 0; h < HH; ++h) {
      float w = wvv[h];
      acc[h].x += w * xv.x;
      acc[h].y += w * xv.y;
    }
  }

  float* pb = partial + ((size_t)sc * BB + b) * (HH * DD) + dh * 512 + tid * 2;
#pragma unroll
  for (int h = 0; h < HH; ++h)
    *reinterpret_cast<float2*>(pb + (size_t)h * DD) = acc[h];
}

// K4: reduce 32 s-chunk partials. grid 512, block 256.
__global__ __launch_bounds__(256) void k_reduce(
    const float* __restrict__ partial, float* __restrict__ out) {
  const int idx = blockIdx.x * 256 + threadIdx.x;
  float s = 0.f;
#pragma unroll
  for (int c = 0; c < 32; ++c) s += partial[(size_t)c * (BB * HH * DD) + idx];
  out[idx] = s;
}

extern "C" void kernel_launch(void* const* d_in, const int* in_sizes, int n_in,
                              void* d_out, int out_size, void* d_ws, size_t ws_size,
                              hipStream_t stream) {
  const float* x = (const float*)d_in[0];     // [8][4096][1024] fp32
  const float* W = (const float*)d_in[1];     // [1024][16] fp32
  const int* mask = (const int*)d_in[2];      // [8][4096] int32
  float* out = (float*)d_out;                 // [8][16384] fp32

  char* ws = (char*)d_ws;
  float* plog    = (float*)ws;                                   // 4 MB
  float* partial = (float*)(ws + (size_t)6 * 1024 * 1024);       // 16 MB
  ushort* wh16   = (ushort*)(ws + (size_t)22 * 1024 * 1024);     // 32 KB
  ushort* wl16   = (ushort*)(ws + (size_t)22 * 1024 * 1024 + 32 * 1024);
  float2* bred   = (float2*)(ws + (size_t)23 * 1024 * 1024);     // 32 KB

  k_prepw<<<64, 256, 0, stream>>>(W, wh16, wl16);
  k_logits<<<1024, 256, 0, stream>>>(x, wh16, wl16, plog);
  k_smpart<<<256, 256, 0, stream>>>(plog, mask, bred);
  k_pool<<<512, 256, 0, stream>>>(x, plog, bred, mask, partial);
  k_reduce<<<512, 256, 0, stream>>>(partial, out);
}